// Round 6
// baseline (205.039 us; speedup 1.0000x reference)
//
#include <hip/hip_runtime.h>

// ---------- types / helpers ----------
typedef __attribute__((ext_vector_type(8))) short short8;    // 8 x bf16
typedef __attribute__((ext_vector_type(4))) short short4v;   // 4 x bf16
typedef __attribute__((ext_vector_type(4))) float floatx4;   // MFMA acc / 16B fp32
typedef __attribute__((ext_vector_type(4))) unsigned int uint4v;
typedef __attribute__((ext_vector_type(2))) unsigned int uint2v;

__device__ __forceinline__ unsigned short f2bf(float f) {
  unsigned u = __float_as_uint(f);
  u += 0x7FFFu + ((u >> 16) & 1u);
  return (unsigned short)(u >> 16);
}
// two fp32 -> dword [bf(f0)][bf(f1)] (validated R4/R5)
__device__ __forceinline__ unsigned pack_bf2(float f0, float f1) {
  unsigned a = __float_as_uint(f0) + 0x8000u;
  unsigned b = __float_as_uint(f1) + 0x8000u;
  return __builtin_amdgcn_perm(b, a, 0x07060302u);
}
__device__ __forceinline__ void async16(const unsigned short* g, unsigned short* l) {
  __builtin_amdgcn_global_load_lds(
      (const __attribute__((address_space(1))) unsigned int*)g,
      (__attribute__((address_space(3))) unsigned int*)l, 16, 0, 0);
}

#define B_   2
#define QN_  2048
#define NDS_ 1024
#define H_   16

// ---------- fp32 -> bf16 elementwise (full activations) ----------
__global__ __launch_bounds__(256) void cvt_bf16(
    const float* __restrict__ in, unsigned short* __restrict__ out) {
  size_t idx = ((size_t)blockIdx.x * 256 + threadIdx.x) * 8;
  floatx4 a = *(const floatx4*)(in + idx);
  floatx4 b = *(const floatx4*)(in + idx + 4);
  uint4v u = {pack_bf2(a[0], a[1]), pack_bf2(a[2], a[3]),
              pack_bf2(b[0], b[1]), pack_bf2(b[2], b[3])};
  *(uint4v*)(out + idx) = u;
}

// ---------- fp32 weights -> bf16 TRANSPOSED (WT[n][k] = W[k][n]) ----------
__global__ __launch_bounds__(256) void cvt_wT(
    const float* __restrict__ Wq, const float* __restrict__ Wk,
    const float* __restrict__ Wv, const float* __restrict__ Wo,
    unsigned short* __restrict__ outbase) {
  const float* W = blockIdx.z == 0 ? Wq : blockIdx.z == 1 ? Wk
                 : blockIdx.z == 2 ? Wv : Wo;
  unsigned short* out = outbase + (size_t)blockIdx.z * (1u << 20);
  __shared__ unsigned short tile[64][65];
  int bi = blockIdx.y, bj = blockIdx.x;
  int c = threadIdx.x & 63, r0 = threadIdx.x >> 6;
#pragma unroll
  for (int i = 0; i < 64; i += 4)
    tile[r0 + i][c] = f2bf(W[(size_t)(bi * 64 + r0 + i) * 1024 + bj * 64 + c]);
  __syncthreads();
#pragma unroll
  for (int i = 0; i < 64; i += 4)
    out[(size_t)(bj * 64 + r0 + i) * 1024 + bi * 64 + c] = tile[c][r0 + i];
}

// ---------- fused QKV GEMM: 128x128 tiles, BK=32, swizzled LDS ----------
// by<32: Q rows (A=full_bf async16), [32,48): K rows, [48,64): V rows
// (A=ds fp32 pack). All outputs coalesced bf16 row-major.
__global__ __launch_bounds__(256) void gemm_qkv(
    const unsigned short* __restrict__ fullbf, const float* __restrict__ ds,
    const unsigned short* __restrict__ WT,  // [WqT][WkT][WvT]
    unsigned short* __restrict__ Qb, unsigned short* __restrict__ Kb,
    unsigned short* __restrict__ Vb) {
  __shared__ __align__(16) unsigned short As[128 * 32];
  __shared__ __align__(16) unsigned short Bs[128 * 32];
  int t = threadIdx.x;
  int lane = t & 63, wave = t >> 6;
  int lrow = lane & 15, quad = lane >> 4;
  int by = blockIdx.y;
  int colBase = blockIdx.x * 128;
  int wr = (wave & 1) * 64, wc = (wave >> 1) * 64;
  int sw = (lrow >> 1) & 3;  // fragment-read swizzle

  int sel = (by < 32) ? 0 : (by < 48 ? 1 : 2);
  const unsigned short* Wt = WT + (size_t)sel * (1u << 20);
  size_t arow0 = (sel == 0) ? (size_t)by * 128
                            : (size_t)(by - (sel == 1 ? 32 : 48)) * 128;

  floatx4 acc[4][4];
#pragma unroll
  for (int mi = 0; mi < 4; ++mi)
#pragma unroll
    for (int ni = 0; ni < 4; ++ni) acc[mi][ni] = (floatx4){0.f, 0.f, 0.f, 0.f};

  for (int k0 = 0; k0 < 1024; k0 += 32) {
    __syncthreads();
    // A staging (swizzled source column: chunk linear holds qcol ^ ((row>>1)&3))
    if (sel == 0) {
#pragma unroll
      for (int it = 0; it < 2; ++it) {
        int linear = it * 256 + t;
        int row = linear >> 2;
        int qg = (linear & 3) ^ ((row >> 1) & 3);
        async16(fullbf + (arow0 + row) * 1024 + k0 + qg * 8, As + linear * 8);
      }
    } else {
#pragma unroll
      for (int it = 0; it < 2; ++it) {
        int linear = it * 256 + t;
        int row = linear >> 2;
        int qg = (linear & 3) ^ ((row >> 1) & 3);
        const float* p = ds + (arow0 + row) * 1024 + k0 + qg * 8;
        floatx4 x = *(const floatx4*)p, y = *(const floatx4*)(p + 4);
        uint4v u = {pack_bf2(x[0], x[1]), pack_bf2(x[2], x[3]),
                    pack_bf2(y[0], y[1]), pack_bf2(y[2], y[3])};
        *(uint4v*)&As[linear * 8] = u;
      }
    }
#pragma unroll
    for (int it = 0; it < 2; ++it) {
      int linear = it * 256 + t;
      int row = linear >> 2;
      int qg = (linear & 3) ^ ((row >> 1) & 3);
      async16(Wt + (size_t)(colBase + row) * 1024 + k0 + qg * 8, Bs + linear * 8);
    }
    __syncthreads();

    short8 af[4], bfr[4];
#pragma unroll
    for (int mi = 0; mi < 4; ++mi)
      af[mi] = *(const short8*)&As[(wr + mi * 16 + lrow) * 32 + (quad ^ sw) * 8];
#pragma unroll
    for (int ni = 0; ni < 4; ++ni)
      bfr[ni] = *(const short8*)&Bs[(wc + ni * 16 + lrow) * 32 + (quad ^ sw) * 8];
#pragma unroll
    for (int mi = 0; mi < 4; ++mi)
#pragma unroll
      for (int ni = 0; ni < 4; ++ni)
        acc[mi][ni] =
            __builtin_amdgcn_mfma_f32_16x16x32_bf16(af[mi], bfr[ni], acc[mi][ni], 0, 0, 0);
  }

  unsigned short* C = (sel == 0) ? Qb : (sel == 1 ? Kb : Vb);
#pragma unroll
  for (int mi = 0; mi < 4; ++mi)
#pragma unroll
    for (int ni = 0; ni < 4; ++ni) {
      int col = colBase + wc + ni * 16 + lrow;
#pragma unroll
      for (int r = 0; r < 4; ++r) {
        size_t row = arow0 + wr + mi * 16 + quad * 4 + r;
        C[row * 1024 + col] = f2bf(acc[mi][ni][r]);
      }
    }
}

// ---------- in-place per-batch 1024x1024 bf16 transpose (V -> Vt) ----------
__global__ __launch_bounds__(256) void transpose_inplace(unsigned short* V) {
  __shared__ unsigned short ta[64][66], tb[64][66];
  int b = blockIdx.y;
  int p = blockIdx.x;  // 0..135 triangular pair index
  int ti = 0, rem = p;
  while (rem >= 16 - ti) { rem -= 16 - ti; ++ti; }
  int tj = ti + rem;
  unsigned short* Vb = V + (size_t)b * (1024 * 1024);
  int t = threadIdx.x;
  int c4 = (t & 15) * 4, r = t >> 4;
#pragma unroll
  for (int i = 0; i < 4; ++i) {
    int row = r + i * 16;
    *(short4v*)&ta[row][c4] =
        *(const short4v*)&Vb[(size_t)(ti * 64 + row) * 1024 + tj * 64 + c4];
    if (ti != tj)
      *(short4v*)&tb[row][c4] =
          *(const short4v*)&Vb[(size_t)(tj * 64 + row) * 1024 + ti * 64 + c4];
  }
  __syncthreads();
#pragma unroll
  for (int i = 0; i < 4; ++i) {
    int row = r + i * 16;
    short4v wa;
#pragma unroll
    for (int e = 0; e < 4; ++e) wa[e] = ta[c4 + e][row];
    *(short4v*)&Vb[(size_t)(tj * 64 + row) * 1024 + ti * 64 + c4] = wa;
    if (ti != tj) {
      short4v wb;
#pragma unroll
      for (int e = 0; e < 4; ++e) wb[e] = tb[c4 + e][row];
      *(short4v*)&Vb[(size_t)(ti * 64 + row) * 1024 + tj * 64 + c4] = wb;
    }
  }
}

// ---------- attention: block-shared dbuf staging, swizzled, S^T form ----------
#define PSTR 40
__global__ __launch_bounds__(256) void attn_kernel(
    const unsigned short* __restrict__ Q,   // [4096][1024] bf16
    const unsigned short* __restrict__ K,   // [2048][1024] bf16
    const unsigned short* __restrict__ V,   // Vt [B][1024 d][1024 kv] bf16
    unsigned short* __restrict__ O) {       // [4096][1024] bf16
  __shared__ __align__(16) unsigned short Ks[2][32 * 64];
  __shared__ __align__(16) unsigned short Vs[2][64 * 32];
  __shared__ __align__(16) unsigned short Pl[4][16 * PSTR];
  int t = threadIdx.x, lane = t & 63, wave = t >> 6;
  int lrow = lane & 15, quad = lane >> 4;
  int bh = blockIdx.y, b = bh >> 4, h = bh & 15;
  int q0 = blockIdx.x * 64, qtile = q0 + wave * 16;
  int swk = lrow & 7, swv = (lrow >> 1) & 3;

  // Q as B-operand: n=q=lrow, k=d=quad*8+j (+32)
  const unsigned short* qp =
      Q + (size_t)(b * QN_ + qtile + lrow) * 1024 + h * 64 + quad * 8;
  short8 qb0 = *(const short8*)qp;
  short8 qb1 = *(const short8*)(qp + 32);

  // swizzled staging sources (chunk term added per iteration)
  int krow = t >> 3, kq = (t & 7) ^ (krow & 7);
  const unsigned short* ksrc =
      K + (size_t)(b * NDS_ + krow) * 1024 + h * 64 + kq * 8;
  int vrow = t >> 2, vq = (t & 3) ^ ((vrow >> 1) & 3);
  const unsigned short* vsrc =
      V + ((size_t)b * 1024 + h * 64 + vrow) * 1024 + vq * 8;

  int c0 = (q0 >= 1058) ? (((q0 - 1058) >> 5) + 1) : 0;
  async16(ksrc + (size_t)c0 * 32 * 1024, &Ks[0][t * 8]);
  async16(vsrc + c0 * 32, &Vs[0][t * 8]);

  floatx4 acc_o[4];
#pragma unroll
  for (int dt = 0; dt < 4; ++dt) acc_o[dt] = (floatx4){0.f, 0.f, 0.f, 0.f};
  float denom = 0.f;
  int t1 = qtile + lrow - 2, t2 = qtile + lrow - 1026;
  unsigned short* P = Pl[wave];
  int buf = 0;

  for (int c = c0; c < 32; ++c) {
    __syncthreads();  // chunk c staged; prior reads of buf^1 complete
    if (c + 1 < 32) {
      async16(ksrc + (size_t)(c + 1) * 32 * 1024, &Ks[buf ^ 1][t * 8]);
      async16(vsrc + (c + 1) * 32, &Vs[buf ^ 1][t * 8]);
    }
    int cb = c * 32;
#pragma unroll
    for (int nt = 0; nt < 2; ++nt) {
      const unsigned short* kb = &Ks[buf][(nt * 16 + lrow) * 64];
      short8 ka0 = *(const short8*)(kb + (quad ^ swk) * 8);
      short8 ka1 = *(const short8*)(kb + ((quad + 4) ^ swk) * 8);
      floatx4 z = (floatx4){0.f, 0.f, 0.f, 0.f};
      z = __builtin_amdgcn_mfma_f32_16x16x32_bf16(ka0, qb0, z, 0, 0, 0);
      z = __builtin_amdgcn_mfma_f32_16x16x32_bf16(ka1, qb1, z, 0, 0, 0);
      float p[4];
#pragma unroll
      for (int r = 0; r < 4; ++r) {
        int j0 = cb + nt * 16 + quad * 4 + r;
        float m = (j0 >= t1 ? 1.f : 0.f) + (j0 >= t2 ? 1.f : 0.f);
        p[r] = m * __expf(z[r] * 0.125f);
        denom += p[r];
      }
      uint2v pw = {pack_bf2(p[0], p[1]), pack_bf2(p[2], p[3])};
      *(uint2v*)&P[lrow * PSTR + nt * 16 + quad * 4] = pw;
    }
    short8 pa = *(const short8*)&P[lrow * PSTR + quad * 8];
#pragma unroll
    for (int dt = 0; dt < 4; ++dt) {
      short8 vf =
          *(const short8*)&Vs[buf][(dt * 16 + lrow) * 32 + (quad ^ swv) * 8];
      acc_o[dt] = __builtin_amdgcn_mfma_f32_16x16x32_bf16(pa, vf, acc_o[dt], 0, 0, 0);
    }
    buf ^= 1;
  }
  denom += __shfl_xor(denom, 16);
  denom += __shfl_xor(denom, 32);
  float dd[4];
#pragma unroll
  for (int r = 0; r < 4; ++r) dd[r] = __shfl(denom, quad * 4 + r);
#pragma unroll
  for (int dt = 0; dt < 4; ++dt)
#pragma unroll
    for (int r = 0; r < 4; ++r) {
      int i = qtile + quad * 4 + r;
      int col = h * 64 + dt * 16 + lrow;
      O[(size_t)(b * QN_ + i) * 1024 + col] = f2bf(acc_o[dt][r] / dd[r]);
    }
}

// ---------- O GEMM: out = Ab @ WoT^T + bo, BM=64, swizzled ----------
__global__ __launch_bounds__(256) void gemm_o(
    const unsigned short* __restrict__ Ab, const unsigned short* __restrict__ WoT,
    const float* __restrict__ bo, float* __restrict__ out) {
  __shared__ __align__(16) unsigned short As[64 * 32];
  __shared__ __align__(16) unsigned short Bs[128 * 32];
  int t = threadIdx.x;
  int lane = t & 63, wave = t >> 6;
  int lrow = lane & 15, quad = lane >> 4;
  size_t rowBase = (size_t)blockIdx.y * 64;
  int colBase = blockIdx.x * 128;
  int wr = (wave & 1) * 32, wc = (wave >> 1) * 64;
  int sw = (lrow >> 1) & 3;

  floatx4 acc[2][4];
#pragma unroll
  for (int mi = 0; mi < 2; ++mi)
#pragma unroll
    for (int ni = 0; ni < 4; ++ni) acc[mi][ni] = (floatx4){0.f, 0.f, 0.f, 0.f};

  for (int k0 = 0; k0 < 1024; k0 += 32) {
    __syncthreads();
    {
      int row = t >> 2;
      int qg = (t & 3) ^ ((row >> 1) & 3);
      async16(Ab + (rowBase + row) * 1024 + k0 + qg * 8, As + t * 8);
    }
#pragma unroll
    for (int it = 0; it < 2; ++it) {
      int linear = it * 256 + t;
      int row = linear >> 2;
      int qg = (linear & 3) ^ ((row >> 1) & 3);
      async16(WoT + (size_t)(colBase + row) * 1024 + k0 + qg * 8, Bs + linear * 8);
    }
    __syncthreads();

    short8 af[2], bfr[4];
#pragma unroll
    for (int mi = 0; mi < 2; ++mi)
      af[mi] = *(const short8*)&As[(wr + mi * 16 + lrow) * 32 + (quad ^ sw) * 8];
#pragma unroll
    for (int ni = 0; ni < 4; ++ni)
      bfr[ni] = *(const short8*)&Bs[(wc + ni * 16 + lrow) * 32 + (quad ^ sw) * 8];
#pragma unroll
    for (int mi = 0; mi < 2; ++mi)
#pragma unroll
      for (int ni = 0; ni < 4; ++ni)
        acc[mi][ni] =
            __builtin_amdgcn_mfma_f32_16x16x32_bf16(af[mi], bfr[ni], acc[mi][ni], 0, 0, 0);
  }

#pragma unroll
  for (int mi = 0; mi < 2; ++mi)
#pragma unroll
    for (int ni = 0; ni < 4; ++ni) {
      int col = colBase + wc + ni * 16 + lrow;
      float badd = bo[col];
#pragma unroll
      for (int r = 0; r < 4; ++r) {
        size_t row = rowBase + wr + mi * 16 + quad * 4 + r;
        out[row * 1024 + col] = acc[mi][ni][r] + badd;
      }
    }
}

// ---------- launch ----------
extern "C" void kernel_launch(void* const* d_in, const int* in_sizes, int n_in,
                              void* d_out, int out_size, void* d_ws, size_t ws_size,
                              hipStream_t stream) {
  const float* full = (const float*)d_in[0];  // [2,2048,1024] fp32
  const float* ds   = (const float*)d_in[1];  // [2,1024,1024] fp32
  const float* Wq   = (const float*)d_in[2];
  const float* Wk   = (const float*)d_in[3];
  const float* Wv   = (const float*)d_in[4];
  const float* Wo   = (const float*)d_in[5];
  const float* bo   = (const float*)d_in[6];
  float* out = (float*)d_out;

  // ws layout (halfwords), 32 MB total:
  unsigned short* ws = (unsigned short*)d_ws;
  unsigned short* Qb      = ws;                     // [0,4M)   4096x1024
  unsigned short* Kb      = ws + (4u << 20);        // [4M,6M)  2048x1024
  unsigned short* Vb      = ws + (6u << 20);        // [6M,8M)  -> Vt in place
  unsigned short* Ab      = ws + (8u << 20);        // [8M,12M) (aliases full_bf)
  unsigned short* full_bf = Ab;                     // dead after gemm_qkv
  unsigned short* WT      = ws + (12u << 20);       // [12M,16M) WqT WkT WvT WoT
  unsigned short* WoT     = WT + 3u * (1u << 20);

  dim3 tb(256);
  cvt_bf16<<<2048, tb, 0, stream>>>(full, full_bf);
  cvt_wT<<<dim3(16, 16, 4), tb, 0, stream>>>(Wq, Wk, Wv, Wo, WT);
  gemm_qkv<<<dim3(8, 64), tb, 0, stream>>>(full_bf, ds, WT, Qb, Kb, Vb);
  transpose_inplace<<<dim3(136, 2), tb, 0, stream>>>(Vb);
  attn_kernel<<<dim3(QN_ / 64, B_ * H_), tb, 0, stream>>>(Qb, Kb, Vb, Ab);
  gemm_o<<<dim3(8, 64), tb, 0, stream>>>(Ab, WoT, bo, out);
}

// Round 7
// 189.163 us; speedup vs baseline: 1.0839x; 1.0839x over previous
//
#include <hip/hip_runtime.h>

// ---------- types / helpers ----------
typedef __attribute__((ext_vector_type(8))) short short8;    // 8 x bf16
typedef __attribute__((ext_vector_type(4))) short short4v;   // 4 x bf16
typedef __attribute__((ext_vector_type(4))) float floatx4;   // MFMA acc / 16B fp32
typedef __attribute__((ext_vector_type(4))) unsigned int uint4v;
typedef __attribute__((ext_vector_type(2))) unsigned int uint2v;

__device__ __forceinline__ unsigned short f2bf(float f) {
  unsigned u = __float_as_uint(f);
  u += 0x7FFFu + ((u >> 16) & 1u);
  return (unsigned short)(u >> 16);
}
// two fp32 -> dword [bf(f0)][bf(f1)] (validated R4+)
__device__ __forceinline__ unsigned pack_bf2(float f0, float f1) {
  unsigned a = __float_as_uint(f0) + 0x8000u;
  unsigned b = __float_as_uint(f1) + 0x8000u;
  return __builtin_amdgcn_perm(b, a, 0x07060302u);
}
__device__ __forceinline__ void async16(const unsigned short* g, unsigned short* l) {
  __builtin_amdgcn_global_load_lds(
      (const __attribute__((address_space(1))) unsigned int*)g,
      (__attribute__((address_space(3))) unsigned int*)l, 16, 0, 0);
}

#define B_   2
#define QN_  2048
#define NDS_ 1024
#define H_   16
// 0.125 * log2(e): exp(s/8) == exp2(s * C_SC)
#define C_SC 0.18033688011f

// ---------- prep: weight transpose->bf16 (blocks 0..1023) + full->bf16 ----------
__global__ __launch_bounds__(256) void prep(
    const float* __restrict__ Wq, const float* __restrict__ Wk,
    const float* __restrict__ Wv, const float* __restrict__ Wo,
    const float* __restrict__ full, unsigned short* __restrict__ WT,
    unsigned short* __restrict__ full_bf) {
  int bid = blockIdx.x;
  if (bid < 1024) {
    int z = bid >> 8, tile = bid & 255;
    const float* W = z == 0 ? Wq : z == 1 ? Wk : z == 2 ? Wv : Wo;
    unsigned short* out = WT + (size_t)z * (1u << 20);
    __shared__ unsigned short tilebuf[64][65];
    int bi = tile >> 4, bj = tile & 15;
    int c = threadIdx.x & 63, r0 = threadIdx.x >> 6;
#pragma unroll
    for (int i = 0; i < 64; i += 4)
      tilebuf[r0 + i][c] = f2bf(W[(size_t)(bi * 64 + r0 + i) * 1024 + bj * 64 + c]);
    __syncthreads();
#pragma unroll
    for (int i = 0; i < 64; i += 4)
      out[(size_t)(bj * 64 + r0 + i) * 1024 + bi * 64 + c] = tilebuf[c][r0 + i];
  } else {
    size_t idx = ((size_t)(bid - 1024) * 256 + threadIdx.x) * 8;
    floatx4 a = *(const floatx4*)(full + idx);
    floatx4 b = *(const floatx4*)(full + idx + 4);
    uint4v u = {pack_bf2(a[0], a[1]), pack_bf2(a[2], a[3]),
                pack_bf2(b[0], b[1]), pack_bf2(b[2], b[3])};
    *(uint4v*)(full_bf + idx) = u;
  }
}

// ---------- fused QKV GEMM: 128x128 tiles, BK=32, swizzled LDS ----------
// by<32: Q rows (A=full_bf async16); [32,48): K rows; [48,64): V rows
// (A=ds fp32 pack). V epilogue writes Vt[b][d][kv] directly (R4-validated).
__global__ __launch_bounds__(256) void gemm_qkv(
    const unsigned short* __restrict__ fullbf, const float* __restrict__ ds,
    const unsigned short* __restrict__ WT,
    unsigned short* __restrict__ Qb, unsigned short* __restrict__ Kb,
    unsigned short* __restrict__ Vt) {
  __shared__ __align__(16) unsigned short As[128 * 32];
  __shared__ __align__(16) unsigned short Bs[128 * 32];
  int t = threadIdx.x;
  int lane = t & 63, wave = t >> 6;
  int lrow = lane & 15, quad = lane >> 4;
  int by = blockIdx.y;
  int colBase = blockIdx.x * 128;
  int wr = (wave & 1) * 64, wc = (wave >> 1) * 64;
  int sw = (lrow >> 1) & 3;

  int sel = (by < 32) ? 0 : (by < 48 ? 1 : 2);
  const unsigned short* Wt = WT + (size_t)sel * (1u << 20);
  size_t arow0 = (sel == 0) ? (size_t)by * 128
                            : (size_t)(by - (sel == 1 ? 32 : 48)) * 128;

  floatx4 acc[4][4];
#pragma unroll
  for (int mi = 0; mi < 4; ++mi)
#pragma unroll
    for (int ni = 0; ni < 4; ++ni) acc[mi][ni] = (floatx4){0.f, 0.f, 0.f, 0.f};

  for (int k0 = 0; k0 < 1024; k0 += 32) {
    __syncthreads();
    if (sel == 0) {
#pragma unroll
      for (int it = 0; it < 2; ++it) {
        int linear = it * 256 + t;
        int row = linear >> 2;
        int qg = (linear & 3) ^ ((row >> 1) & 3);
        async16(fullbf + (arow0 + row) * 1024 + k0 + qg * 8, As + linear * 8);
      }
    } else {
#pragma unroll
      for (int it = 0; it < 2; ++it) {
        int linear = it * 256 + t;
        int row = linear >> 2;
        int qg = (linear & 3) ^ ((row >> 1) & 3);
        const float* p = ds + (arow0 + row) * 1024 + k0 + qg * 8;
        floatx4 x = *(const floatx4*)p, y = *(const floatx4*)(p + 4);
        uint4v u = {pack_bf2(x[0], x[1]), pack_bf2(x[2], x[3]),
                    pack_bf2(y[0], y[1]), pack_bf2(y[2], y[3])};
        *(uint4v*)&As[linear * 8] = u;
      }
    }
#pragma unroll
    for (int it = 0; it < 2; ++it) {
      int linear = it * 256 + t;
      int row = linear >> 2;
      int qg = (linear & 3) ^ ((row >> 1) & 3);
      async16(Wt + (size_t)(colBase + row) * 1024 + k0 + qg * 8, Bs + linear * 8);
    }
    __syncthreads();

    short8 af[4], bfr[4];
#pragma unroll
    for (int mi = 0; mi < 4; ++mi)
      af[mi] = *(const short8*)&As[(wr + mi * 16 + lrow) * 32 + (quad ^ sw) * 8];
#pragma unroll
    for (int ni = 0; ni < 4; ++ni)
      bfr[ni] = *(const short8*)&Bs[(wc + ni * 16 + lrow) * 32 + (quad ^ sw) * 8];
#pragma unroll
    for (int mi = 0; mi < 4; ++mi)
#pragma unroll
      for (int ni = 0; ni < 4; ++ni)
        acc[mi][ni] =
            __builtin_amdgcn_mfma_f32_16x16x32_bf16(af[mi], bfr[ni], acc[mi][ni], 0, 0, 0);
  }

#pragma unroll
  for (int mi = 0; mi < 4; ++mi)
#pragma unroll
    for (int ni = 0; ni < 4; ++ni) {
      int col = colBase + wc + ni * 16 + lrow;
      if (sel == 2) {  // V: write transposed Vt[b][d=col][kv]
        size_t r0g = arow0 + wr + mi * 16 + quad * 4;
        size_t b = r0g >> 10, kv = r0g & 1023;
        short4v pk;
#pragma unroll
        for (int r = 0; r < 4; ++r) pk[r] = (short)f2bf(acc[mi][ni][r]);
        *(short4v*)&Vt[b * (1u << 20) + (size_t)col * 1024 + kv] = pk;
      } else {
        unsigned short* C = (sel == 0) ? Qb : Kb;
#pragma unroll
        for (int r = 0; r < 4; ++r) {
          size_t row = arow0 + wr + mi * 16 + quad * 4 + r;
          C[row * 1024 + col] = f2bf(acc[mi][ni][r]);
        }
      }
    }
}

// ---------- attention: dbuf staging + S^T form + uniform-mask fast path ----------
#define PSTR 40
__global__ __launch_bounds__(256) void attn_kernel(
    const unsigned short* __restrict__ Q,   // [4096][1024] bf16
    const unsigned short* __restrict__ K,   // [2048][1024] bf16
    const unsigned short* __restrict__ V,   // Vt [B][1024 d][1024 kv] bf16
    unsigned short* __restrict__ O) {       // [4096][1024] bf16
  __shared__ __align__(16) unsigned short Ks[2][32 * 64];
  __shared__ __align__(16) unsigned short Vs[2][64 * 32];
  __shared__ __align__(16) unsigned short Pl[4][16 * PSTR];
  int t = threadIdx.x, lane = t & 63, wave = t >> 6;
  int lrow = lane & 15, quad = lane >> 4;
  int bh = blockIdx.y, b = bh >> 4, h = bh & 15;
  int q0 = blockIdx.x * 64, qtile = q0 + wave * 16;
  int swk = lrow & 7, swv = (lrow >> 1) & 3;

  const unsigned short* qp =
      Q + (size_t)(b * QN_ + qtile + lrow) * 1024 + h * 64 + quad * 8;
  short8 qb0 = *(const short8*)qp;
  short8 qb1 = *(const short8*)(qp + 32);

  int krow = t >> 3, kq = (t & 7) ^ (krow & 7);
  const unsigned short* ksrc =
      K + (size_t)(b * NDS_ + krow) * 1024 + h * 64 + kq * 8;
  int vrow = t >> 2, vq = (t & 3) ^ ((vrow >> 1) & 3);
  const unsigned short* vsrc =
      V + ((size_t)b * 1024 + h * 64 + vrow) * 1024 + vq * 8;

  int c0 = (q0 >= 1058) ? (((q0 - 1058) >> 5) + 1) : 0;
  async16(ksrc + (size_t)c0 * 32 * 1024, &Ks[0][t * 8]);
  async16(vsrc + c0 * 32, &Vs[0][t * 8]);
  const unsigned short* kpre = ksrc + (size_t)(c0 + 1) * 32 * 1024;
  const unsigned short* vpre = vsrc + (c0 + 1) * 32;

  floatx4 acc_o[4];
#pragma unroll
  for (int dt = 0; dt < 4; ++dt) acc_o[dt] = (floatx4){0.f, 0.f, 0.f, 0.f};
  float den0 = 0.f, den1 = 0.f;
  int t1 = qtile + lrow - 2, t2 = qtile + lrow - 1026;
  unsigned short* P = Pl[wave];
  int buf = 0;

  for (int c = c0; c < 32; ++c) {
    __syncthreads();  // chunk c staged; prior reads of buf^1 done
    if (c + 1 < 32) {
      async16(kpre, &Ks[buf ^ 1][t * 8]);
      async16(vpre, &Vs[buf ^ 1][t * 8]);
      kpre += 32 * 1024;
      vpre += 32;
    }
    int cb = c * 32;
    // wave-uniform mask classification
    bool fast2 = (cb >= qtile + 13);                       // m == 2 everywhere
    bool fast1 = (cb <= qtile - 34) && (cb >= qtile - 1011);  // m == 1 everywhere
    if (fast1 || fast2) {
      float bias = fast2 ? 1.f : 0.f;  // x2 folded into exponent
#pragma unroll
      for (int nt = 0; nt < 2; ++nt) {
        const unsigned short* kb = &Ks[buf][(nt * 16 + lrow) * 64];
        short8 ka0 = *(const short8*)(kb + (quad ^ swk) * 8);
        short8 ka1 = *(const short8*)(kb + ((quad + 4) ^ swk) * 8);
        floatx4 z = (floatx4){0.f, 0.f, 0.f, 0.f};
        z = __builtin_amdgcn_mfma_f32_16x16x32_bf16(ka0, qb0, z, 0, 0, 0);
        z = __builtin_amdgcn_mfma_f32_16x16x32_bf16(ka1, qb1, z, 0, 0, 0);
        float p[4];
#pragma unroll
        for (int r = 0; r < 4; ++r) {
          p[r] = __builtin_amdgcn_exp2f(fmaf(z[r], C_SC, bias));
          if (nt == 0) den0 += p[r]; else den1 += p[r];
        }
        uint2v pw = {pack_bf2(p[0], p[1]), pack_bf2(p[2], p[3])};
        *(uint2v*)&P[lrow * PSTR + nt * 16 + quad * 4] = pw;
      }
    } else {
#pragma unroll
      for (int nt = 0; nt < 2; ++nt) {
        const unsigned short* kb = &Ks[buf][(nt * 16 + lrow) * 64];
        short8 ka0 = *(const short8*)(kb + (quad ^ swk) * 8);
        short8 ka1 = *(const short8*)(kb + ((quad + 4) ^ swk) * 8);
        floatx4 z = (floatx4){0.f, 0.f, 0.f, 0.f};
        z = __builtin_amdgcn_mfma_f32_16x16x32_bf16(ka0, qb0, z, 0, 0, 0);
        z = __builtin_amdgcn_mfma_f32_16x16x32_bf16(ka1, qb1, z, 0, 0, 0);
        float p[4];
#pragma unroll
        for (int r = 0; r < 4; ++r) {
          int j0 = cb + nt * 16 + quad * 4 + r;
          float m = (j0 >= t1 ? 1.f : 0.f) + (j0 >= t2 ? 1.f : 0.f);
          p[r] = m * __builtin_amdgcn_exp2f(z[r] * C_SC);
          if (nt == 0) den0 += p[r]; else den1 += p[r];
        }
        uint2v pw = {pack_bf2(p[0], p[1]), pack_bf2(p[2], p[3])};
        *(uint2v*)&P[lrow * PSTR + nt * 16 + quad * 4] = pw;
      }
    }
    short8 pa = *(const short8*)&P[lrow * PSTR + quad * 8];
#pragma unroll
    for (int dt = 0; dt < 4; ++dt) {
      short8 vf =
          *(const short8*)&Vs[buf][(dt * 16 + lrow) * 32 + (quad ^ swv) * 8];
      acc_o[dt] = __builtin_amdgcn_mfma_f32_16x16x32_bf16(pa, vf, acc_o[dt], 0, 0, 0);
    }
    buf ^= 1;
  }
  float denom = den0 + den1;
  denom += __shfl_xor(denom, 16);
  denom += __shfl_xor(denom, 32);
  float dd[4];
#pragma unroll
  for (int r = 0; r < 4; ++r) dd[r] = __shfl(denom, quad * 4 + r);
#pragma unroll
  for (int dt = 0; dt < 4; ++dt)
#pragma unroll
    for (int r = 0; r < 4; ++r) {
      int i = qtile + quad * 4 + r;
      int col = h * 64 + dt * 16 + lrow;
      O[(size_t)(b * QN_ + i) * 1024 + col] = f2bf(acc_o[dt][r] / dd[r]);
    }
}

// ---------- O GEMM: out = Ab @ WoT^T + bo, BM=64, swizzled ----------
__global__ __launch_bounds__(256) void gemm_o(
    const unsigned short* __restrict__ Ab, const unsigned short* __restrict__ WoT,
    const float* __restrict__ bo, float* __restrict__ out) {
  __shared__ __align__(16) unsigned short As[64 * 32];
  __shared__ __align__(16) unsigned short Bs[128 * 32];
  int t = threadIdx.x;
  int lane = t & 63, wave = t >> 6;
  int lrow = lane & 15, quad = lane >> 4;
  size_t rowBase = (size_t)blockIdx.y * 64;
  int colBase = blockIdx.x * 128;
  int wr = (wave & 1) * 32, wc = (wave >> 1) * 64;
  int sw = (lrow >> 1) & 3;

  floatx4 acc[2][4];
#pragma unroll
  for (int mi = 0; mi < 2; ++mi)
#pragma unroll
    for (int ni = 0; ni < 4; ++ni) acc[mi][ni] = (floatx4){0.f, 0.f, 0.f, 0.f};

  for (int k0 = 0; k0 < 1024; k0 += 32) {
    __syncthreads();
    {
      int row = t >> 2;
      int qg = (t & 3) ^ ((row >> 1) & 3);
      async16(Ab + (rowBase + row) * 1024 + k0 + qg * 8, As + t * 8);
    }
#pragma unroll
    for (int it = 0; it < 2; ++it) {
      int linear = it * 256 + t;
      int row = linear >> 2;
      int qg = (linear & 3) ^ ((row >> 1) & 3);
      async16(WoT + (size_t)(colBase + row) * 1024 + k0 + qg * 8, Bs + linear * 8);
    }
    __syncthreads();

    short8 af[2], bfr[4];
#pragma unroll
    for (int mi = 0; mi < 2; ++mi)
      af[mi] = *(const short8*)&As[(wr + mi * 16 + lrow) * 32 + (quad ^ sw) * 8];
#pragma unroll
    for (int ni = 0; ni < 4; ++ni)
      bfr[ni] = *(const short8*)&Bs[(wc + ni * 16 + lrow) * 32 + (quad ^ sw) * 8];
#pragma unroll
    for (int mi = 0; mi < 2; ++mi)
#pragma unroll
      for (int ni = 0; ni < 4; ++ni)
        acc[mi][ni] =
            __builtin_amdgcn_mfma_f32_16x16x32_bf16(af[mi], bfr[ni], acc[mi][ni], 0, 0, 0);
  }

#pragma unroll
  for (int mi = 0; mi < 2; ++mi)
#pragma unroll
    for (int ni = 0; ni < 4; ++ni) {
      int col = colBase + wc + ni * 16 + lrow;
      float badd = bo[col];
#pragma unroll
      for (int r = 0; r < 4; ++r) {
        size_t row = rowBase + wr + mi * 16 + quad * 4 + r;
        out[row * 1024 + col] = acc[mi][ni][r] + badd;
      }
    }
}

// ---------- launch ----------
extern "C" void kernel_launch(void* const* d_in, const int* in_sizes, int n_in,
                              void* d_out, int out_size, void* d_ws, size_t ws_size,
                              hipStream_t stream) {
  const float* full = (const float*)d_in[0];  // [2,2048,1024] fp32
  const float* ds   = (const float*)d_in[1];  // [2,1024,1024] fp32
  const float* Wq   = (const float*)d_in[2];
  const float* Wk   = (const float*)d_in[3];
  const float* Wv   = (const float*)d_in[4];
  const float* Wo   = (const float*)d_in[5];
  const float* bo   = (const float*)d_in[6];
  float* out = (float*)d_out;

  // ws layout (halfwords), 32 MB total:
  unsigned short* ws = (unsigned short*)d_ws;
  unsigned short* Qb      = ws;                     // [0,4M)   4096x1024
  unsigned short* Kb      = ws + (4u << 20);        // [4M,6M)  2048x1024
  unsigned short* Vt      = ws + (6u << 20);        // [6M,8M)  [B][1024 d][1024 kv]
  unsigned short* Ab      = ws + (8u << 20);        // [8M,12M) (aliases full_bf)
  unsigned short* full_bf = Ab;                     // dead after gemm_qkv
  unsigned short* WT      = ws + (12u << 20);       // [12M,16M) WqT WkT WvT WoT
  unsigned short* WoT     = WT + 3u * (1u << 20);

  dim3 tb(256);
  prep<<<3072, tb, 0, stream>>>(Wq, Wk, Wv, Wo, full, WT, full_bf);
  gemm_qkv<<<dim3(8, 64), tb, 0, stream>>>(full_bf, ds, WT, Qb, Kb, Vt);
  attn_kernel<<<dim3(QN_ / 64, B_ * H_), tb, 0, stream>>>(Qb, Kb, Vt, Ab);
  gemm_o<<<dim3(8, 64), tb, 0, stream>>>(Ab, WoT, bo, out);
}

// Round 8
// 177.802 us; speedup vs baseline: 1.1532x; 1.0639x over previous
//
#include <hip/hip_runtime.h>

// ---------- types / helpers ----------
typedef __attribute__((ext_vector_type(8))) short short8;    // 8 x bf16
typedef __attribute__((ext_vector_type(4))) short short4v;   // 4 x bf16
typedef __attribute__((ext_vector_type(4))) float floatx4;   // MFMA acc / 16B fp32
typedef __attribute__((ext_vector_type(4))) unsigned int uint4v;
typedef __attribute__((ext_vector_type(2))) unsigned int uint2v;

__device__ __forceinline__ unsigned short f2bf(float f) {
  unsigned u = __float_as_uint(f);
  u += 0x7FFFu + ((u >> 16) & 1u);
  return (unsigned short)(u >> 16);
}
// two fp32 -> dword [bf(f0)][bf(f1)] (validated R4+)
__device__ __forceinline__ unsigned pack_bf2(float f0, float f1) {
  unsigned a = __float_as_uint(f0) + 0x8000u;
  unsigned b = __float_as_uint(f1) + 0x8000u;
  return __builtin_amdgcn_perm(b, a, 0x07060302u);
}
__device__ __forceinline__ void async16(const unsigned short* g, unsigned short* l) {
  __builtin_amdgcn_global_load_lds(
      (const __attribute__((address_space(1))) unsigned int*)g,
      (__attribute__((address_space(3))) unsigned int*)l, 16, 0, 0);
}

#define B_   2
#define QN_  2048
#define NDS_ 1024
#define H_   16
// 0.125 * log2(e): exp(s/8) == exp2(s * C_SC)
#define C_SC 0.18033688011f

// ---------- prep: fp32 weights -> bf16 transposed (WT[n][k] = W[k][n]) ----------
__global__ __launch_bounds__(256) void prep(
    const float* __restrict__ Wq, const float* __restrict__ Wk,
    const float* __restrict__ Wv, const float* __restrict__ Wo,
    unsigned short* __restrict__ WT) {
  int bid = blockIdx.x;
  int z = bid >> 8, tile = bid & 255;
  const float* W = z == 0 ? Wq : z == 1 ? Wk : z == 2 ? Wv : Wo;
  unsigned short* out = WT + (size_t)z * (1u << 20);
  __shared__ unsigned short tilebuf[64][65];
  int bi = tile >> 4, bj = tile & 15;
  int c = threadIdx.x & 63, r0 = threadIdx.x >> 6;
#pragma unroll
  for (int i = 0; i < 64; i += 4)
    tilebuf[r0 + i][c] = f2bf(W[(size_t)(bi * 64 + r0 + i) * 1024 + bj * 64 + c]);
  __syncthreads();
#pragma unroll
  for (int i = 0; i < 64; i += 4)
    out[(size_t)(bj * 64 + r0 + i) * 1024 + bi * 64 + c] = tilebuf[c][r0 + i];
}

// ---------- fused QKV GEMM: 128x128 tiles, BK=64, swizzled LDS ----------
// by<32: Q rows (A=full fp32); [32,48): K rows; [48,64): V rows (A=ds fp32).
// A staged via fp32->bf16 pack; W via async16. V epilogue writes Vt directly.
__global__ __launch_bounds__(256) void gemm_qkv(
    const float* __restrict__ full, const float* __restrict__ ds,
    const unsigned short* __restrict__ WT,
    unsigned short* __restrict__ Qb, unsigned short* __restrict__ Kb,
    unsigned short* __restrict__ Vt) {
  __shared__ __align__(16) unsigned short As[128 * 64];
  __shared__ __align__(16) unsigned short Bs[128 * 64];
  int t = threadIdx.x;
  int lane = t & 63, wave = t >> 6;
  int lrow = lane & 15, quad = lane >> 4;
  int by = blockIdx.y;
  int colBase = blockIdx.x * 128;
  int wr = (wave & 1) * 64, wc = (wave >> 1) * 64;
  int sw = lrow & 7;

  int sel = (by < 32) ? 0 : (by < 48 ? 1 : 2);
  const unsigned short* Wt = WT + (size_t)sel * (1u << 20);
  const float* Afp = (sel == 0) ? full : ds;
  size_t arow0 = (sel == 0) ? (size_t)by * 128
                            : (size_t)(by - (sel == 1 ? 32 : 48)) * 128;

  floatx4 acc[4][4];
#pragma unroll
  for (int mi = 0; mi < 4; ++mi)
#pragma unroll
    for (int ni = 0; ni < 4; ++ni) acc[mi][ni] = (floatx4){0.f, 0.f, 0.f, 0.f};

  for (int k0 = 0; k0 < 1024; k0 += 64) {
    __syncthreads();
    // stage A (fp32 pack) and B (async16): 128x64 tiles = 1024 chunks each
#pragma unroll
    for (int it = 0; it < 4; ++it) {
      int linear = it * 256 + t;
      int row = linear >> 3;
      int cg = (linear & 7) ^ (row & 7);  // swizzled source chunk-col
      const float* p = Afp + (arow0 + row) * 1024 + k0 + cg * 8;
      floatx4 x = *(const floatx4*)p, y = *(const floatx4*)(p + 4);
      uint4v u = {pack_bf2(x[0], x[1]), pack_bf2(x[2], x[3]),
                  pack_bf2(y[0], y[1]), pack_bf2(y[2], y[3])};
      *(uint4v*)&As[linear * 8] = u;
      async16(Wt + (size_t)(colBase + row) * 1024 + k0 + cg * 8, Bs + linear * 8);
    }
    __syncthreads();

#pragma unroll
    for (int ks = 0; ks < 2; ++ks) {
      int fc = ((ks * 4 + quad) ^ sw) * 8;
      short8 af[4], bfr[4];
#pragma unroll
      for (int mi = 0; mi < 4; ++mi)
        af[mi] = *(const short8*)&As[(wr + mi * 16 + lrow) * 64 + fc];
#pragma unroll
      for (int ni = 0; ni < 4; ++ni)
        bfr[ni] = *(const short8*)&Bs[(wc + ni * 16 + lrow) * 64 + fc];
#pragma unroll
      for (int mi = 0; mi < 4; ++mi)
#pragma unroll
        for (int ni = 0; ni < 4; ++ni)
          acc[mi][ni] =
              __builtin_amdgcn_mfma_f32_16x16x32_bf16(af[mi], bfr[ni], acc[mi][ni], 0, 0, 0);
    }
  }

#pragma unroll
  for (int mi = 0; mi < 4; ++mi)
#pragma unroll
    for (int ni = 0; ni < 4; ++ni) {
      int col = colBase + wc + ni * 16 + lrow;
      if (sel == 2) {  // V: write transposed Vt[b][d=col][kv]
        size_t r0g = arow0 + wr + mi * 16 + quad * 4;
        size_t b = r0g >> 10, kv = r0g & 1023;
        short4v pk;
#pragma unroll
        for (int r = 0; r < 4; ++r) pk[r] = (short)f2bf(acc[mi][ni][r]);
        *(short4v*)&Vt[b * (1u << 20) + (size_t)col * 1024 + kv] = pk;
      } else {
        unsigned short* C = (sel == 0) ? Qb : Kb;
#pragma unroll
        for (int r = 0; r < 4; ++r) {
          size_t row = arow0 + wr + mi * 16 + quad * 4 + r;
          C[row * 1024 + col] = f2bf(acc[mi][ni][r]);
        }
      }
    }
}

// ---------- attention: dbuf staging + S^T form + uniform-mask fast path ----------
#define PSTR 40
__global__ __launch_bounds__(256) void attn_kernel(
    const unsigned short* __restrict__ Q,   // [4096][1024] bf16
    const unsigned short* __restrict__ K,   // [2048][1024] bf16
    const unsigned short* __restrict__ V,   // Vt [B][1024 d][1024 kv] bf16
    unsigned short* __restrict__ O) {       // [4096][1024] bf16
  __shared__ __align__(16) unsigned short Ks[2][32 * 64];
  __shared__ __align__(16) unsigned short Vs[2][64 * 32];
  __shared__ __align__(16) unsigned short Pl[4][16 * PSTR];
  int t = threadIdx.x, lane = t & 63, wave = t >> 6;
  int lrow = lane & 15, quad = lane >> 4;
  int bh = blockIdx.y, b = bh >> 4, h = bh & 15;
  int q0 = blockIdx.x * 64, qtile = q0 + wave * 16;
  int swk = lrow & 7, swv = (lrow >> 1) & 3;

  const unsigned short* qp =
      Q + (size_t)(b * QN_ + qtile + lrow) * 1024 + h * 64 + quad * 8;
  short8 qb0 = *(const short8*)qp;
  short8 qb1 = *(const short8*)(qp + 32);

  int krow = t >> 3, kq = (t & 7) ^ (krow & 7);
  const unsigned short* ksrc =
      K + (size_t)(b * NDS_ + krow) * 1024 + h * 64 + kq * 8;
  int vrow = t >> 2, vq = (t & 3) ^ ((vrow >> 1) & 3);
  const unsigned short* vsrc =
      V + ((size_t)b * 1024 + h * 64 + vrow) * 1024 + vq * 8;

  int c0 = (q0 >= 1058) ? (((q0 - 1058) >> 5) + 1) : 0;
  async16(ksrc + (size_t)c0 * 32 * 1024, &Ks[0][t * 8]);
  async16(vsrc + c0 * 32, &Vs[0][t * 8]);
  const unsigned short* kpre = ksrc + (size_t)(c0 + 1) * 32 * 1024;
  const unsigned short* vpre = vsrc + (c0 + 1) * 32;

  floatx4 acc_o[4];
#pragma unroll
  for (int dt = 0; dt < 4; ++dt) acc_o[dt] = (floatx4){0.f, 0.f, 0.f, 0.f};
  float den0 = 0.f, den1 = 0.f;
  int t1 = qtile + lrow - 2, t2 = qtile + lrow - 1026;
  unsigned short* P = Pl[wave];
  int buf = 0;

  for (int c = c0; c < 32; ++c) {
    __syncthreads();  // chunk c staged; prior reads of buf^1 done
    if (c + 1 < 32) {
      async16(kpre, &Ks[buf ^ 1][t * 8]);
      async16(vpre, &Vs[buf ^ 1][t * 8]);
      kpre += 32 * 1024;
      vpre += 32;
    }
    int cb = c * 32;
    bool fast2 = (cb >= qtile + 13);                          // m == 2 everywhere
    bool fast1 = (cb <= qtile - 34) && (cb >= qtile - 1011);  // m == 1 everywhere
    if (fast1 || fast2) {
      float bias = fast2 ? 1.f : 0.f;  // x2 folded into exponent
#pragma unroll
      for (int nt = 0; nt < 2; ++nt) {
        const unsigned short* kb = &Ks[buf][(nt * 16 + lrow) * 64];
        short8 ka0 = *(const short8*)(kb + (quad ^ swk) * 8);
        short8 ka1 = *(const short8*)(kb + ((quad + 4) ^ swk) * 8);
        floatx4 z = (floatx4){0.f, 0.f, 0.f, 0.f};
        z = __builtin_amdgcn_mfma_f32_16x16x32_bf16(ka0, qb0, z, 0, 0, 0);
        z = __builtin_amdgcn_mfma_f32_16x16x32_bf16(ka1, qb1, z, 0, 0, 0);
        float p[4];
#pragma unroll
        for (int r = 0; r < 4; ++r) {
          p[r] = __builtin_amdgcn_exp2f(fmaf(z[r], C_SC, bias));
          if (nt == 0) den0 += p[r]; else den1 += p[r];
        }
        uint2v pw = {pack_bf2(p[0], p[1]), pack_bf2(p[2], p[3])};
        *(uint2v*)&P[lrow * PSTR + nt * 16 + quad * 4] = pw;
      }
    } else {
#pragma unroll
      for (int nt = 0; nt < 2; ++nt) {
        const unsigned short* kb = &Ks[buf][(nt * 16 + lrow) * 64];
        short8 ka0 = *(const short8*)(kb + (quad ^ swk) * 8);
        short8 ka1 = *(const short8*)(kb + ((quad + 4) ^ swk) * 8);
        floatx4 z = (floatx4){0.f, 0.f, 0.f, 0.f};
        z = __builtin_amdgcn_mfma_f32_16x16x32_bf16(ka0, qb0, z, 0, 0, 0);
        z = __builtin_amdgcn_mfma_f32_16x16x32_bf16(ka1, qb1, z, 0, 0, 0);
        float p[4];
#pragma unroll
        for (int r = 0; r < 4; ++r) {
          int j0 = cb + nt * 16 + quad * 4 + r;
          float m = (j0 >= t1 ? 1.f : 0.f) + (j0 >= t2 ? 1.f : 0.f);
          p[r] = m * __builtin_amdgcn_exp2f(z[r] * C_SC);
          if (nt == 0) den0 += p[r]; else den1 += p[r];
        }
        uint2v pw = {pack_bf2(p[0], p[1]), pack_bf2(p[2], p[3])};
        *(uint2v*)&P[lrow * PSTR + nt * 16 + quad * 4] = pw;
      }
    }
    short8 pa = *(const short8*)&P[lrow * PSTR + quad * 8];
#pragma unroll
    for (int dt = 0; dt < 4; ++dt) {
      short8 vf =
          *(const short8*)&Vs[buf][(dt * 16 + lrow) * 32 + (quad ^ swv) * 8];
      acc_o[dt] = __builtin_amdgcn_mfma_f32_16x16x32_bf16(pa, vf, acc_o[dt], 0, 0, 0);
    }
    buf ^= 1;
  }
  float denom = den0 + den1;
  denom += __shfl_xor(denom, 16);
  denom += __shfl_xor(denom, 32);
  float dd[4];
#pragma unroll
  for (int r = 0; r < 4; ++r) dd[r] = __shfl(denom, quad * 4 + r);
#pragma unroll
  for (int dt = 0; dt < 4; ++dt)
#pragma unroll
    for (int r = 0; r < 4; ++r) {
      int i = qtile + quad * 4 + r;
      int col = h * 64 + dt * 16 + lrow;
      O[(size_t)(b * QN_ + i) * 1024 + col] = f2bf(acc_o[dt][r] / dd[r]);
    }
}

// ---------- O GEMM: out = Ab @ WoT^T + bo, BM=64, BK=64, swizzled ----------
__global__ __launch_bounds__(256) void gemm_o(
    const unsigned short* __restrict__ Ab, const unsigned short* __restrict__ WoT,
    const float* __restrict__ bo, float* __restrict__ out) {
  __shared__ __align__(16) unsigned short As[64 * 64];
  __shared__ __align__(16) unsigned short Bs[128 * 64];
  int t = threadIdx.x;
  int lane = t & 63, wave = t >> 6;
  int lrow = lane & 15, quad = lane >> 4;
  size_t rowBase = (size_t)blockIdx.y * 64;
  int colBase = blockIdx.x * 128;
  int wr = (wave & 1) * 32, wc = (wave >> 1) * 64;
  int sw = lrow & 7;

  floatx4 acc[2][4];
#pragma unroll
  for (int mi = 0; mi < 2; ++mi)
#pragma unroll
    for (int ni = 0; ni < 4; ++ni) acc[mi][ni] = (floatx4){0.f, 0.f, 0.f, 0.f};

  for (int k0 = 0; k0 < 1024; k0 += 64) {
    __syncthreads();
#pragma unroll
    for (int it = 0; it < 2; ++it) {  // A: 64x64 = 512 chunks
      int linear = it * 256 + t;
      int row = linear >> 3;
      int cg = (linear & 7) ^ (row & 7);
      async16(Ab + (rowBase + row) * 1024 + k0 + cg * 8, As + linear * 8);
    }
#pragma unroll
    for (int it = 0; it < 4; ++it) {  // B: 128x64 = 1024 chunks
      int linear = it * 256 + t;
      int row = linear >> 3;
      int cg = (linear & 7) ^ (row & 7);
      async16(WoT + (size_t)(colBase + row) * 1024 + k0 + cg * 8, Bs + linear * 8);
    }
    __syncthreads();

#pragma unroll
    for (int ks = 0; ks < 2; ++ks) {
      int fc = ((ks * 4 + quad) ^ sw) * 8;
      short8 af[2], bfr[4];
#pragma unroll
      for (int mi = 0; mi < 2; ++mi)
        af[mi] = *(const short8*)&As[(wr + mi * 16 + lrow) * 64 + fc];
#pragma unroll
      for (int ni = 0; ni < 4; ++ni)
        bfr[ni] = *(const short8*)&Bs[(wc + ni * 16 + lrow) * 64 + fc];
#pragma unroll
      for (int mi = 0; mi < 2; ++mi)
#pragma unroll
        for (int ni = 0; ni < 4; ++ni)
          acc[mi][ni] =
              __builtin_amdgcn_mfma_f32_16x16x32_bf16(af[mi], bfr[ni], acc[mi][ni], 0, 0, 0);
    }
  }

#pragma unroll
  for (int mi = 0; mi < 2; ++mi)
#pragma unroll
    for (int ni = 0; ni < 4; ++ni) {
      int col = colBase + wc + ni * 16 + lrow;
      float badd = bo[col];
#pragma unroll
      for (int r = 0; r < 4; ++r) {
        size_t row = rowBase + wr + mi * 16 + quad * 4 + r;
        out[row * 1024 + col] = acc[mi][ni][r] + badd;
      }
    }
}

// ---------- launch ----------
extern "C" void kernel_launch(void* const* d_in, const int* in_sizes, int n_in,
                              void* d_out, int out_size, void* d_ws, size_t ws_size,
                              hipStream_t stream) {
  const float* full = (const float*)d_in[0];  // [2,2048,1024] fp32
  const float* ds   = (const float*)d_in[1];  // [2,1024,1024] fp32
  const float* Wq   = (const float*)d_in[2];
  const float* Wk   = (const float*)d_in[3];
  const float* Wv   = (const float*)d_in[4];
  const float* Wo   = (const float*)d_in[5];
  const float* bo   = (const float*)d_in[6];
  float* out = (float*)d_out;

  // ws layout (halfwords), 32 MB total:
  unsigned short* ws = (unsigned short*)d_ws;
  unsigned short* Qb  = ws;                     // [0,4M)   4096x1024
  unsigned short* Kb  = ws + (4u << 20);        // [4M,6M)  2048x1024
  unsigned short* Vt  = ws + (6u << 20);        // [6M,8M)  [B][1024 d][1024 kv]
  unsigned short* Ab  = ws + (8u << 20);        // [8M,12M) 4096x1024
  unsigned short* WT  = ws + (12u << 20);       // [12M,16M) WqT WkT WvT WoT
  unsigned short* WoT = WT + 3u * (1u << 20);

  dim3 tb(256);
  prep<<<1024, tb, 0, stream>>>(Wq, Wk, Wv, Wo, WT);
  gemm_qkv<<<dim3(8, 64), tb, 0, stream>>>(full, ds, WT, Qb, Kb, Vt);
  attn_kernel<<<dim3(QN_ / 64, B_ * H_), tb, 0, stream>>>(Qb, Kb, Vt, Ab);
  gemm_o<<<dim3(8, 64), tb, 0, stream>>>(Ab, WoT, bo, out);
}

// Round 9
// 172.776 us; speedup vs baseline: 1.1867x; 1.0291x over previous
//
#include <hip/hip_runtime.h>

// ---------- types / helpers ----------
typedef __attribute__((ext_vector_type(8))) short short8;    // 8 x bf16
typedef __attribute__((ext_vector_type(4))) short short4v;   // 4 x bf16
typedef __attribute__((ext_vector_type(4))) float floatx4;   // MFMA acc / 16B fp32
typedef __attribute__((ext_vector_type(4))) unsigned int uint4v;
typedef __attribute__((ext_vector_type(2))) unsigned int uint2v;

__device__ __forceinline__ unsigned short f2bf(float f) {
  unsigned u = __float_as_uint(f);
  u += 0x7FFFu + ((u >> 16) & 1u);
  return (unsigned short)(u >> 16);
}
// two fp32 -> dword [bf(f0)][bf(f1)] (validated R4+)
__device__ __forceinline__ unsigned pack_bf2(float f0, float f1) {
  unsigned a = __float_as_uint(f0) + 0x8000u;
  unsigned b = __float_as_uint(f1) + 0x8000u;
  return __builtin_amdgcn_perm(b, a, 0x07060302u);
}
__device__ __forceinline__ void async16(const unsigned short* g, unsigned short* l) {
  __builtin_amdgcn_global_load_lds(
      (const __attribute__((address_space(1))) unsigned int*)g,
      (__attribute__((address_space(3))) unsigned int*)l, 16, 0, 0);
}

#define B_   2
#define QN_  2048
#define NDS_ 1024
#define H_   16
// 0.125 * log2(e): exp(s/8) == exp2(s * C_SC)
#define C_SC 0.18033688011f

// ---------- prep: fp32 weights -> bf16 transposed (WT[n][k] = W[k][n]) ----------
__global__ __launch_bounds__(256) void prep(
    const float* __restrict__ Wq, const float* __restrict__ Wk,
    const float* __restrict__ Wv, const float* __restrict__ Wo,
    unsigned short* __restrict__ WT) {
  int bid = blockIdx.x;
  int z = bid >> 8, tile = bid & 255;
  const float* W = z == 0 ? Wq : z == 1 ? Wk : z == 2 ? Wv : Wo;
  unsigned short* out = WT + (size_t)z * (1u << 20);
  __shared__ unsigned short tilebuf[64][65];
  int bi = tile >> 4, bj = tile & 15;
  int c = threadIdx.x & 63, r0 = threadIdx.x >> 6;
#pragma unroll
  for (int i = 0; i < 64; i += 4)
    tilebuf[r0 + i][c] = f2bf(W[(size_t)(bi * 64 + r0 + i) * 1024 + bj * 64 + c]);
  __syncthreads();
#pragma unroll
  for (int i = 0; i < 64; i += 4)
    out[(size_t)(bj * 64 + r0 + i) * 1024 + bi * 64 + c] = tilebuf[c][r0 + i];
}

// ---------- fused QKV GEMM: 128x128 tile, BK=64, 512 threads (8 waves) ----------
// by<32: Q rows (A=full fp32); [32,48): K rows; [48,64): V rows (A=ds fp32).
// A staged via fp32->bf16 pack; W via async16. V epilogue writes Vt directly.
__global__ __launch_bounds__(512) void gemm_qkv(
    const float* __restrict__ full, const float* __restrict__ ds,
    const unsigned short* __restrict__ WT,
    unsigned short* __restrict__ Qb, unsigned short* __restrict__ Kb,
    unsigned short* __restrict__ Vt) {
  __shared__ __align__(16) unsigned short As[128 * 64];
  __shared__ __align__(16) unsigned short Bs[128 * 64];
  int t = threadIdx.x;
  int lane = t & 63, wave = t >> 6;           // 8 waves
  int lrow = lane & 15, quad = lane >> 4;
  int by = blockIdx.y;
  int colBase = blockIdx.x * 128;
  int wr = (wave & 3) * 32, wc = (wave >> 2) * 64;  // 4 row-groups x 2 col-groups
  int sw = lrow & 7;

  int sel = (by < 32) ? 0 : (by < 48 ? 1 : 2);
  const unsigned short* Wt = WT + (size_t)sel * (1u << 20);
  const float* Afp = (sel == 0) ? full : ds;
  size_t arow0 = (sel == 0) ? (size_t)by * 128
                            : (size_t)(by - (sel == 1 ? 32 : 48)) * 128;

  floatx4 acc[2][4];
#pragma unroll
  for (int mi = 0; mi < 2; ++mi)
#pragma unroll
    for (int ni = 0; ni < 4; ++ni) acc[mi][ni] = (floatx4){0.f, 0.f, 0.f, 0.f};

  for (int k0 = 0; k0 < 1024; k0 += 64) {
    __syncthreads();
    // stage A (fp32->bf16 pack) and B (async16): 128x64 tiles = 1024 chunks each
#pragma unroll
    for (int it = 0; it < 2; ++it) {
      int linear = it * 512 + t;
      int row = linear >> 3;
      int cg = (linear & 7) ^ (row & 7);  // swizzled source chunk-col
      const float* p = Afp + (arow0 + row) * 1024 + k0 + cg * 8;
      floatx4 x = *(const floatx4*)p, y = *(const floatx4*)(p + 4);
      uint4v u = {pack_bf2(x[0], x[1]), pack_bf2(x[2], x[3]),
                  pack_bf2(y[0], y[1]), pack_bf2(y[2], y[3])};
      *(uint4v*)&As[linear * 8] = u;
      async16(Wt + (size_t)(colBase + row) * 1024 + k0 + cg * 8, Bs + linear * 8);
    }
    __syncthreads();

#pragma unroll
    for (int ks = 0; ks < 2; ++ks) {
      int fc = ((ks * 4 + quad) ^ sw) * 8;
      short8 af[2], bfr[4];
#pragma unroll
      for (int mi = 0; mi < 2; ++mi)
        af[mi] = *(const short8*)&As[(wr + mi * 16 + lrow) * 64 + fc];
#pragma unroll
      for (int ni = 0; ni < 4; ++ni)
        bfr[ni] = *(const short8*)&Bs[(wc + ni * 16 + lrow) * 64 + fc];
#pragma unroll
      for (int mi = 0; mi < 2; ++mi)
#pragma unroll
        for (int ni = 0; ni < 4; ++ni)
          acc[mi][ni] =
              __builtin_amdgcn_mfma_f32_16x16x32_bf16(af[mi], bfr[ni], acc[mi][ni], 0, 0, 0);
    }
  }

#pragma unroll
  for (int mi = 0; mi < 2; ++mi)
#pragma unroll
    for (int ni = 0; ni < 4; ++ni) {
      int col = colBase + wc + ni * 16 + lrow;
      if (sel == 2) {  // V: write transposed Vt[b][d=col][kv]
        size_t r0g = arow0 + wr + mi * 16 + quad * 4;
        size_t b = r0g >> 10, kv = r0g & 1023;
        short4v pk;
#pragma unroll
        for (int r = 0; r < 4; ++r) pk[r] = (short)f2bf(acc[mi][ni][r]);
        *(short4v*)&Vt[b * (1u << 20) + (size_t)col * 1024 + kv] = pk;
      } else {
        unsigned short* C = (sel == 0) ? Qb : Kb;
#pragma unroll
        for (int r = 0; r < 4; ++r) {
          size_t row = arow0 + wr + mi * 16 + quad * 4 + r;
          C[row * 1024 + col] = f2bf(acc[mi][ni][r]);
        }
      }
    }
}

// ---------- attention: dbuf staging + S^T form + uniform-mask fast path ----------
#define PSTR 40
__global__ __launch_bounds__(256) void attn_kernel(
    const unsigned short* __restrict__ Q,   // [4096][1024] bf16
    const unsigned short* __restrict__ K,   // [2048][1024] bf16
    const unsigned short* __restrict__ V,   // Vt [B][1024 d][1024 kv] bf16
    unsigned short* __restrict__ O) {       // [4096][1024] bf16
  __shared__ __align__(16) unsigned short Ks[2][32 * 64];
  __shared__ __align__(16) unsigned short Vs[2][64 * 32];
  __shared__ __align__(16) unsigned short Pl[4][16 * PSTR];
  int t = threadIdx.x, lane = t & 63, wave = t >> 6;
  int lrow = lane & 15, quad = lane >> 4;
  int bh = blockIdx.y, b = bh >> 4, h = bh & 15;
  int q0 = blockIdx.x * 64, qtile = q0 + wave * 16;
  int swk = lrow & 7, swv = (lrow >> 1) & 3;

  const unsigned short* qp =
      Q + (size_t)(b * QN_ + qtile + lrow) * 1024 + h * 64 + quad * 8;
  short8 qb0 = *(const short8*)qp;
  short8 qb1 = *(const short8*)(qp + 32);

  int krow = t >> 3, kq = (t & 7) ^ (krow & 7);
  const unsigned short* ksrc =
      K + (size_t)(b * NDS_ + krow) * 1024 + h * 64 + kq * 8;
  int vrow = t >> 2, vq = (t & 3) ^ ((vrow >> 1) & 3);
  const unsigned short* vsrc =
      V + ((size_t)b * 1024 + h * 64 + vrow) * 1024 + vq * 8;

  int c0 = (q0 >= 1058) ? (((q0 - 1058) >> 5) + 1) : 0;
  async16(ksrc + (size_t)c0 * 32 * 1024, &Ks[0][t * 8]);
  async16(vsrc + c0 * 32, &Vs[0][t * 8]);
  const unsigned short* kpre = ksrc + (size_t)(c0 + 1) * 32 * 1024;
  const unsigned short* vpre = vsrc + (c0 + 1) * 32;

  floatx4 acc_o[4];
#pragma unroll
  for (int dt = 0; dt < 4; ++dt) acc_o[dt] = (floatx4){0.f, 0.f, 0.f, 0.f};
  float den0 = 0.f, den1 = 0.f;
  int t1 = qtile + lrow - 2, t2 = qtile + lrow - 1026;
  unsigned short* P = Pl[wave];
  int buf = 0;

  for (int c = c0; c < 32; ++c) {
    __syncthreads();  // chunk c staged; prior reads of buf^1 done
    if (c + 1 < 32) {
      async16(kpre, &Ks[buf ^ 1][t * 8]);
      async16(vpre, &Vs[buf ^ 1][t * 8]);
      kpre += 32 * 1024;
      vpre += 32;
    }
    int cb = c * 32;
    bool fast2 = (cb >= qtile + 13);                          // m == 2 everywhere
    bool fast1 = (cb <= qtile - 34) && (cb >= qtile - 1011);  // m == 1 everywhere
    if (fast1 || fast2) {
      float bias = fast2 ? 1.f : 0.f;  // x2 folded into exponent
#pragma unroll
      for (int nt = 0; nt < 2; ++nt) {
        const unsigned short* kb = &Ks[buf][(nt * 16 + lrow) * 64];
        short8 ka0 = *(const short8*)(kb + (quad ^ swk) * 8);
        short8 ka1 = *(const short8*)(kb + ((quad + 4) ^ swk) * 8);
        floatx4 z = (floatx4){0.f, 0.f, 0.f, 0.f};
        z = __builtin_amdgcn_mfma_f32_16x16x32_bf16(ka0, qb0, z, 0, 0, 0);
        z = __builtin_amdgcn_mfma_f32_16x16x32_bf16(ka1, qb1, z, 0, 0, 0);
        float p[4];
#pragma unroll
        for (int r = 0; r < 4; ++r) {
          p[r] = __builtin_amdgcn_exp2f(fmaf(z[r], C_SC, bias));
          if (nt == 0) den0 += p[r]; else den1 += p[r];
        }
        uint2v pw = {pack_bf2(p[0], p[1]), pack_bf2(p[2], p[3])};
        *(uint2v*)&P[lrow * PSTR + nt * 16 + quad * 4] = pw;
      }
    } else {
#pragma unroll
      for (int nt = 0; nt < 2; ++nt) {
        const unsigned short* kb = &Ks[buf][(nt * 16 + lrow) * 64];
        short8 ka0 = *(const short8*)(kb + (quad ^ swk) * 8);
        short8 ka1 = *(const short8*)(kb + ((quad + 4) ^ swk) * 8);
        floatx4 z = (floatx4){0.f, 0.f, 0.f, 0.f};
        z = __builtin_amdgcn_mfma_f32_16x16x32_bf16(ka0, qb0, z, 0, 0, 0);
        z = __builtin_amdgcn_mfma_f32_16x16x32_bf16(ka1, qb1, z, 0, 0, 0);
        float p[4];
#pragma unroll
        for (int r = 0; r < 4; ++r) {
          int j0 = cb + nt * 16 + quad * 4 + r;
          float m = (j0 >= t1 ? 1.f : 0.f) + (j0 >= t2 ? 1.f : 0.f);
          p[r] = m * __builtin_amdgcn_exp2f(z[r] * C_SC);
          if (nt == 0) den0 += p[r]; else den1 += p[r];
        }
        uint2v pw = {pack_bf2(p[0], p[1]), pack_bf2(p[2], p[3])};
        *(uint2v*)&P[lrow * PSTR + nt * 16 + quad * 4] = pw;
      }
    }
    short8 pa = *(const short8*)&P[lrow * PSTR + quad * 8];
#pragma unroll
    for (int dt = 0; dt < 4; ++dt) {
      short8 vf =
          *(const short8*)&Vs[buf][(dt * 16 + lrow) * 32 + (quad ^ swv) * 8];
      acc_o[dt] = __builtin_amdgcn_mfma_f32_16x16x32_bf16(pa, vf, acc_o[dt], 0, 0, 0);
    }
    buf ^= 1;
  }
  float denom = den0 + den1;
  denom += __shfl_xor(denom, 16);
  denom += __shfl_xor(denom, 32);
  float dd[4];
#pragma unroll
  for (int r = 0; r < 4; ++r) dd[r] = __shfl(denom, quad * 4 + r);
#pragma unroll
  for (int dt = 0; dt < 4; ++dt)
#pragma unroll
    for (int r = 0; r < 4; ++r) {
      int i = qtile + quad * 4 + r;
      int col = h * 64 + dt * 16 + lrow;
      O[(size_t)(b * QN_ + i) * 1024 + col] = f2bf(acc_o[dt][r] / dd[r]);
    }
}

// ---------- O GEMM: 64x128 tile, BK=64, 512 threads (8 waves) ----------
__global__ __launch_bounds__(512) void gemm_o(
    const unsigned short* __restrict__ Ab, const unsigned short* __restrict__ WoT,
    const float* __restrict__ bo, float* __restrict__ out) {
  __shared__ __align__(16) unsigned short As[64 * 64];
  __shared__ __align__(16) unsigned short Bs[128 * 64];
  int t = threadIdx.x;
  int lane = t & 63, wave = t >> 6;  // 8 waves
  int lrow = lane & 15, quad = lane >> 4;
  size_t rowBase = (size_t)blockIdx.y * 64;
  int colBase = blockIdx.x * 128;
  int wr = (wave & 1) * 32, wc = (wave >> 1) * 32;  // 2 row x 4 col groups
  int sw = lrow & 7;

  floatx4 acc[2][2];
#pragma unroll
  for (int mi = 0; mi < 2; ++mi)
#pragma unroll
    for (int ni = 0; ni < 2; ++ni) acc[mi][ni] = (floatx4){0.f, 0.f, 0.f, 0.f};

  for (int k0 = 0; k0 < 1024; k0 += 64) {
    __syncthreads();
    {  // A: 64x64 = 512 chunks
      int row = t >> 3;
      int cg = (t & 7) ^ (row & 7);
      async16(Ab + (rowBase + row) * 1024 + k0 + cg * 8, As + t * 8);
    }
#pragma unroll
    for (int it = 0; it < 2; ++it) {  // B: 128x64 = 1024 chunks
      int linear = it * 512 + t;
      int row = linear >> 3;
      int cg = (linear & 7) ^ (row & 7);
      async16(WoT + (size_t)(colBase + row) * 1024 + k0 + cg * 8, Bs + linear * 8);
    }
    __syncthreads();

#pragma unroll
    for (int ks = 0; ks < 2; ++ks) {
      int fc = ((ks * 4 + quad) ^ sw) * 8;
      short8 af[2], bfr[2];
#pragma unroll
      for (int mi = 0; mi < 2; ++mi)
        af[mi] = *(const short8*)&As[(wr + mi * 16 + lrow) * 64 + fc];
#pragma unroll
      for (int ni = 0; ni < 2; ++ni)
        bfr[ni] = *(const short8*)&Bs[(wc + ni * 16 + lrow) * 64 + fc];
#pragma unroll
      for (int mi = 0; mi < 2; ++mi)
#pragma unroll
        for (int ni = 0; ni < 2; ++ni)
          acc[mi][ni] =
              __builtin_amdgcn_mfma_f32_16x16x32_bf16(af[mi], bfr[ni], acc[mi][ni], 0, 0, 0);
    }
  }

#pragma unroll
  for (int mi = 0; mi < 2; ++mi)
#pragma unroll
    for (int ni = 0; ni < 2; ++ni) {
      int col = colBase + wc + ni * 16 + lrow;
      float badd = bo[col];
#pragma unroll
      for (int r = 0; r < 4; ++r) {
        size_t row = rowBase + wr + mi * 16 + quad * 4 + r;
        out[row * 1024 + col] = acc[mi][ni][r] + badd;
      }
    }
}

// ---------- launch ----------
extern "C" void kernel_launch(void* const* d_in, const int* in_sizes, int n_in,
                              void* d_out, int out_size, void* d_ws, size_t ws_size,
                              hipStream_t stream) {
  const float* full = (const float*)d_in[0];  // [2,2048,1024] fp32
  const float* ds   = (const float*)d_in[1];  // [2,1024,1024] fp32
  const float* Wq   = (const float*)d_in[2];
  const float* Wk   = (const float*)d_in[3];
  const float* Wv   = (const float*)d_in[4];
  const float* Wo   = (const float*)d_in[5];
  const float* bo   = (const float*)d_in[6];
  float* out = (float*)d_out;

  // ws layout (halfwords), 32 MB total:
  unsigned short* ws = (unsigned short*)d_ws;
  unsigned short* Qb  = ws;                     // [0,4M)   4096x1024
  unsigned short* Kb  = ws + (4u << 20);        // [4M,6M)  2048x1024
  unsigned short* Vt  = ws + (6u << 20);        // [6M,8M)  [B][1024 d][1024 kv]
  unsigned short* Ab  = ws + (8u << 20);        // [8M,12M) 4096x1024
  unsigned short* WT  = ws + (12u << 20);       // [12M,16M) WqT WkT WvT WoT
  unsigned short* WoT = WT + 3u * (1u << 20);

  prep<<<1024, 256, 0, stream>>>(Wq, Wk, Wv, Wo, WT);
  gemm_qkv<<<dim3(8, 64), 512, 0, stream>>>(full, ds, WT, Qb, Kb, Vt);
  attn_kernel<<<dim3(QN_ / 64, B_ * H_), 256, 0, stream>>>(Qb, Kb, Vt, Ab);
  gemm_o<<<dim3(8, 64), 512, 0, stream>>>(Ab, WoT, bo, out);
}

// Round 10
// 166.786 us; speedup vs baseline: 1.2294x; 1.0359x over previous
//
#include <hip/hip_runtime.h>

// ---------- types / helpers ----------
typedef __attribute__((ext_vector_type(8))) short short8;    // 8 x bf16
typedef __attribute__((ext_vector_type(4))) short short4v;   // 4 x bf16
typedef __attribute__((ext_vector_type(4))) float floatx4;   // MFMA acc / 16B fp32
typedef __attribute__((ext_vector_type(4))) unsigned int uint4v;
typedef __attribute__((ext_vector_type(2))) unsigned int uint2v;

__device__ __forceinline__ unsigned short f2bf(float f) {
  unsigned u = __float_as_uint(f);
  u += 0x7FFFu + ((u >> 16) & 1u);
  return (unsigned short)(u >> 16);
}
// two fp32 -> dword [bf(f0)][bf(f1)] (validated R4+)
__device__ __forceinline__ unsigned pack_bf2(float f0, float f1) {
  unsigned a = __float_as_uint(f0) + 0x8000u;
  unsigned b = __float_as_uint(f1) + 0x8000u;
  return __builtin_amdgcn_perm(b, a, 0x07060302u);
}
__device__ __forceinline__ void async16(const unsigned short* g, unsigned short* l) {
  __builtin_amdgcn_global_load_lds(
      (const __attribute__((address_space(1))) unsigned int*)g,
      (__attribute__((address_space(3))) unsigned int*)l, 16, 0, 0);
}

#define B_   2
#define QN_  2048
#define NDS_ 1024
#define H_   16
// 0.125 * log2(e): exp(s/8) == exp2(s * C_SC)
#define C_SC 0.18033688011f

// ---------- prep: fp32 weights -> bf16 transposed (WT[n][k] = W[k][n]) ----------
__global__ __launch_bounds__(256) void prep(
    const float* __restrict__ Wq, const float* __restrict__ Wk,
    const float* __restrict__ Wv, const float* __restrict__ Wo,
    unsigned short* __restrict__ WT) {
  int bid = blockIdx.x;
  int z = bid >> 8, tile = bid & 255;
  const float* W = z == 0 ? Wq : z == 1 ? Wk : z == 2 ? Wv : Wo;
  unsigned short* out = WT + (size_t)z * (1u << 20);
  __shared__ unsigned short tilebuf[64][65];
  int bi = tile >> 4, bj = tile & 15;
  int c = threadIdx.x & 63, r0 = threadIdx.x >> 6;
#pragma unroll
  for (int i = 0; i < 64; i += 4)
    tilebuf[r0 + i][c] = f2bf(W[(size_t)(bi * 64 + r0 + i) * 1024 + bj * 64 + c]);
  __syncthreads();
#pragma unroll
  for (int i = 0; i < 64; i += 4)
    out[(size_t)(bj * 64 + r0 + i) * 1024 + bi * 64 + c] = tilebuf[c][r0 + i];
}

// ---------- fused QKV GEMM: 128x128 tile, BK=64, 512 threads (8 waves) ----------
// grid (x=row-tile 0..63, y=col-tile 0..7): linear id % 8 == row%8, so all 8
// col-tiles of one A row-tile land on ONE XCD (A fetched into a single L2).
__global__ __launch_bounds__(512) void gemm_qkv(
    const float* __restrict__ full, const float* __restrict__ ds,
    const unsigned short* __restrict__ WT,
    unsigned short* __restrict__ Qb, unsigned short* __restrict__ Kb,
    unsigned short* __restrict__ Vt) {
  __shared__ __align__(16) unsigned short As[128 * 64];
  __shared__ __align__(16) unsigned short Bs[128 * 64];
  int t = threadIdx.x;
  int lane = t & 63, wave = t >> 6;           // 8 waves
  int lrow = lane & 15, quad = lane >> 4;
  int by = blockIdx.x;                         // row-tile (XCD-swizzled)
  int colBase = blockIdx.y * 128;
  int wr = (wave & 3) * 32, wc = (wave >> 2) * 64;  // 4 row-groups x 2 col-groups
  int sw = lrow & 7;

  int sel = (by < 32) ? 0 : (by < 48 ? 1 : 2);
  const unsigned short* Wt = WT + (size_t)sel * (1u << 20);
  const float* Afp = (sel == 0) ? full : ds;
  size_t arow0 = (sel == 0) ? (size_t)by * 128
                            : (size_t)(by - (sel == 1 ? 32 : 48)) * 128;

  floatx4 acc[2][4];
#pragma unroll
  for (int mi = 0; mi < 2; ++mi)
#pragma unroll
    for (int ni = 0; ni < 4; ++ni) acc[mi][ni] = (floatx4){0.f, 0.f, 0.f, 0.f};

  for (int k0 = 0; k0 < 1024; k0 += 64) {
    __syncthreads();
#pragma unroll
    for (int it = 0; it < 2; ++it) {
      int linear = it * 512 + t;
      int row = linear >> 3;
      int cg = (linear & 7) ^ (row & 7);  // swizzled source chunk-col
      const float* p = Afp + (arow0 + row) * 1024 + k0 + cg * 8;
      floatx4 x = *(const floatx4*)p, y = *(const floatx4*)(p + 4);
      uint4v u = {pack_bf2(x[0], x[1]), pack_bf2(x[2], x[3]),
                  pack_bf2(y[0], y[1]), pack_bf2(y[2], y[3])};
      *(uint4v*)&As[linear * 8] = u;
      async16(Wt + (size_t)(colBase + row) * 1024 + k0 + cg * 8, Bs + linear * 8);
    }
    __syncthreads();

#pragma unroll
    for (int ks = 0; ks < 2; ++ks) {
      int fc = ((ks * 4 + quad) ^ sw) * 8;
      short8 af[2], bfr[4];
#pragma unroll
      for (int mi = 0; mi < 2; ++mi)
        af[mi] = *(const short8*)&As[(wr + mi * 16 + lrow) * 64 + fc];
#pragma unroll
      for (int ni = 0; ni < 4; ++ni)
        bfr[ni] = *(const short8*)&Bs[(wc + ni * 16 + lrow) * 64 + fc];
#pragma unroll
      for (int mi = 0; mi < 2; ++mi)
#pragma unroll
        for (int ni = 0; ni < 4; ++ni)
          acc[mi][ni] =
              __builtin_amdgcn_mfma_f32_16x16x32_bf16(af[mi], bfr[ni], acc[mi][ni], 0, 0, 0);
    }
  }

#pragma unroll
  for (int mi = 0; mi < 2; ++mi)
#pragma unroll
    for (int ni = 0; ni < 4; ++ni) {
      int col = colBase + wc + ni * 16 + lrow;
      if (sel == 2) {  // V: write transposed Vt[b][d=col][kv]
        size_t r0g = arow0 + wr + mi * 16 + quad * 4;
        size_t b = r0g >> 10, kv = r0g & 1023;
        short4v pk;
#pragma unroll
        for (int r = 0; r < 4; ++r) pk[r] = (short)f2bf(acc[mi][ni][r]);
        *(short4v*)&Vt[b * (1u << 20) + (size_t)col * 1024 + kv] = pk;
      } else {
        unsigned short* C = (sel == 0) ? Qb : Kb;
#pragma unroll
        for (int r = 0; r < 4; ++r) {
          size_t row = arow0 + wr + mi * 16 + quad * 4 + r;
          C[row * 1024 + col] = f2bf(acc[mi][ni][r]);
        }
      }
    }
}

// ---------- attention: 128 q-rows/block (8 waves), dbuf staging, S^T form ----------
#define PSTR 40
__global__ __launch_bounds__(512) void attn_kernel(
    const unsigned short* __restrict__ Q,   // [4096][1024] bf16
    const unsigned short* __restrict__ K,   // [2048][1024] bf16
    const unsigned short* __restrict__ V,   // Vt [B][1024 d][1024 kv] bf16
    unsigned short* __restrict__ O) {       // [4096][1024] bf16
  __shared__ __align__(16) unsigned short Ks[2][32 * 64];
  __shared__ __align__(16) unsigned short Vs[2][64 * 32];
  __shared__ __align__(16) unsigned short Pl[8][16 * PSTR];
  int t = threadIdx.x, lane = t & 63, wave = t >> 6;  // 8 waves
  int lrow = lane & 15, quad = lane >> 4;
  int bh = blockIdx.y, b = bh >> 4, h = bh & 15;
  int q0 = blockIdx.x * 128, qtile = q0 + wave * 16;
  int swk = lrow & 7, swv = (lrow >> 1) & 3;

  const unsigned short* qp =
      Q + (size_t)(b * QN_ + qtile + lrow) * 1024 + h * 64 + quad * 8;
  short8 qb0 = *(const short8*)qp;
  short8 qb1 = *(const short8*)(qp + 32);

  // staging split: threads <256 stage K (32x64), >=256 stage V (64x32)
  int ts = t & 255;
  int krow = ts >> 3, kq = (ts & 7) ^ (krow & 7);
  const unsigned short* ksrc =
      K + (size_t)(b * NDS_ + krow) * 1024 + h * 64 + kq * 8;
  int vrow = ts >> 2, vq = (ts & 3) ^ ((vrow >> 1) & 3);
  const unsigned short* vsrc =
      V + ((size_t)b * 1024 + h * 64 + vrow) * 1024 + vq * 8;

  int c0 = (q0 >= 1058) ? (((q0 - 1058) >> 5) + 1) : 0;
  if (t < 256) async16(ksrc + (size_t)c0 * 32 * 1024, &Ks[0][ts * 8]);
  else         async16(vsrc + c0 * 32, &Vs[0][ts * 8]);
  const unsigned short* kpre = ksrc + (size_t)(c0 + 1) * 32 * 1024;
  const unsigned short* vpre = vsrc + (c0 + 1) * 32;

  floatx4 acc_o[4];
#pragma unroll
  for (int dt = 0; dt < 4; ++dt) acc_o[dt] = (floatx4){0.f, 0.f, 0.f, 0.f};
  float den0 = 0.f, den1 = 0.f;
  int t1 = qtile + lrow - 2, t2 = qtile + lrow - 1026;
  unsigned short* P = Pl[wave];
  int buf = 0;

  for (int c = c0; c < 32; ++c) {
    __syncthreads();  // chunk c staged; prior reads of buf^1 done
    if (c + 1 < 32) {
      if (t < 256) async16(kpre, &Ks[buf ^ 1][ts * 8]);
      else         async16(vpre, &Vs[buf ^ 1][ts * 8]);
      kpre += 32 * 1024;
      vpre += 32;
    }
    int cb = c * 32;
    bool fast2 = (cb >= qtile + 13);                          // m == 2 everywhere
    bool fast1 = (cb <= qtile - 34) && (cb >= qtile - 1011);  // m == 1 everywhere
    if (fast1 || fast2) {
      float bias = fast2 ? 1.f : 0.f;  // x2 folded into exponent
#pragma unroll
      for (int nt = 0; nt < 2; ++nt) {
        const unsigned short* kb = &Ks[buf][(nt * 16 + lrow) * 64];
        short8 ka0 = *(const short8*)(kb + (quad ^ swk) * 8);
        short8 ka1 = *(const short8*)(kb + ((quad + 4) ^ swk) * 8);
        floatx4 z = (floatx4){0.f, 0.f, 0.f, 0.f};
        z = __builtin_amdgcn_mfma_f32_16x16x32_bf16(ka0, qb0, z, 0, 0, 0);
        z = __builtin_amdgcn_mfma_f32_16x16x32_bf16(ka1, qb1, z, 0, 0, 0);
        float p[4];
#pragma unroll
        for (int r = 0; r < 4; ++r) {
          p[r] = __builtin_amdgcn_exp2f(fmaf(z[r], C_SC, bias));
          if (nt == 0) den0 += p[r]; else den1 += p[r];
        }
        uint2v pw = {pack_bf2(p[0], p[1]), pack_bf2(p[2], p[3])};
        *(uint2v*)&P[lrow * PSTR + nt * 16 + quad * 4] = pw;
      }
    } else {
#pragma unroll
      for (int nt = 0; nt < 2; ++nt) {
        const unsigned short* kb = &Ks[buf][(nt * 16 + lrow) * 64];
        short8 ka0 = *(const short8*)(kb + (quad ^ swk) * 8);
        short8 ka1 = *(const short8*)(kb + ((quad + 4) ^ swk) * 8);
        floatx4 z = (floatx4){0.f, 0.f, 0.f, 0.f};
        z = __builtin_amdgcn_mfma_f32_16x16x32_bf16(ka0, qb0, z, 0, 0, 0);
        z = __builtin_amdgcn_mfma_f32_16x16x32_bf16(ka1, qb1, z, 0, 0, 0);
        float p[4];
#pragma unroll
        for (int r = 0; r < 4; ++r) {
          int j0 = cb + nt * 16 + quad * 4 + r;
          float m = (j0 >= t1 ? 1.f : 0.f) + (j0 >= t2 ? 1.f : 0.f);
          p[r] = m * __builtin_amdgcn_exp2f(z[r] * C_SC);
          if (nt == 0) den0 += p[r]; else den1 += p[r];
        }
        uint2v pw = {pack_bf2(p[0], p[1]), pack_bf2(p[2], p[3])};
        *(uint2v*)&P[lrow * PSTR + nt * 16 + quad * 4] = pw;
      }
    }
    short8 pa = *(const short8*)&P[lrow * PSTR + quad * 8];
#pragma unroll
    for (int dt = 0; dt < 4; ++dt) {
      short8 vf =
          *(const short8*)&Vs[buf][(dt * 16 + lrow) * 32 + (quad ^ swv) * 8];
      acc_o[dt] = __builtin_amdgcn_mfma_f32_16x16x32_bf16(pa, vf, acc_o[dt], 0, 0, 0);
    }
    buf ^= 1;
  }
  float denom = den0 + den1;
  denom += __shfl_xor(denom, 16);
  denom += __shfl_xor(denom, 32);
  float dd[4];
#pragma unroll
  for (int r = 0; r < 4; ++r) dd[r] = __shfl(denom, quad * 4 + r);
#pragma unroll
  for (int dt = 0; dt < 4; ++dt)
#pragma unroll
    for (int r = 0; r < 4; ++r) {
      int i = qtile + quad * 4 + r;
      int col = h * 64 + dt * 16 + lrow;
      O[(size_t)(b * QN_ + i) * 1024 + col] = f2bf(acc_o[dt][r] / dd[r]);
    }
}

// ---------- O GEMM: 64x128 tile, BK=64, 512 threads, XCD-swizzled grid ----------
__global__ __launch_bounds__(512) void gemm_o(
    const unsigned short* __restrict__ Ab, const unsigned short* __restrict__ WoT,
    const float* __restrict__ bo, float* __restrict__ out) {
  __shared__ __align__(16) unsigned short As[64 * 64];
  __shared__ __align__(16) unsigned short Bs[128 * 64];
  int t = threadIdx.x;
  int lane = t & 63, wave = t >> 6;  // 8 waves
  int lrow = lane & 15, quad = lane >> 4;
  size_t rowBase = (size_t)blockIdx.x * 64;   // row-tile (XCD-swizzled)
  int colBase = blockIdx.y * 128;
  int wr = (wave & 1) * 32, wc = (wave >> 1) * 32;  // 2 row x 4 col groups
  int sw = lrow & 7;

  floatx4 acc[2][2];
#pragma unroll
  for (int mi = 0; mi < 2; ++mi)
#pragma unroll
    for (int ni = 0; ni < 2; ++ni) acc[mi][ni] = (floatx4){0.f, 0.f, 0.f, 0.f};

  for (int k0 = 0; k0 < 1024; k0 += 64) {
    __syncthreads();
    {  // A: 64x64 = 512 chunks
      int row = t >> 3;
      int cg = (t & 7) ^ (row & 7);
      async16(Ab + (rowBase + row) * 1024 + k0 + cg * 8, As + t * 8);
    }
#pragma unroll
    for (int it = 0; it < 2; ++it) {  // B: 128x64 = 1024 chunks
      int linear = it * 512 + t;
      int row = linear >> 3;
      int cg = (linear & 7) ^ (row & 7);
      async16(WoT + (size_t)(colBase + row) * 1024 + k0 + cg * 8, Bs + linear * 8);
    }
    __syncthreads();

#pragma unroll
    for (int ks = 0; ks < 2; ++ks) {
      int fc = ((ks * 4 + quad) ^ sw) * 8;
      short8 af[2], bfr[2];
#pragma unroll
      for (int mi = 0; mi < 2; ++mi)
        af[mi] = *(const short8*)&As[(wr + mi * 16 + lrow) * 64 + fc];
#pragma unroll
      for (int ni = 0; ni < 2; ++ni)
        bfr[ni] = *(const short8*)&Bs[(wc + ni * 16 + lrow) * 64 + fc];
#pragma unroll
      for (int mi = 0; mi < 2; ++mi)
#pragma unroll
        for (int ni = 0; ni < 2; ++ni)
          acc[mi][ni] =
              __builtin_amdgcn_mfma_f32_16x16x32_bf16(af[mi], bfr[ni], acc[mi][ni], 0, 0, 0);
    }
  }

#pragma unroll
  for (int mi = 0; mi < 2; ++mi)
#pragma unroll
    for (int ni = 0; ni < 2; ++ni) {
      int col = colBase + wc + ni * 16 + lrow;
      float badd = bo[col];
#pragma unroll
      for (int r = 0; r < 4; ++r) {
        size_t row = rowBase + wr + mi * 16 + quad * 4 + r;
        out[row * 1024 + col] = acc[mi][ni][r] + badd;
      }
    }
}

// ---------- launch ----------
extern "C" void kernel_launch(void* const* d_in, const int* in_sizes, int n_in,
                              void* d_out, int out_size, void* d_ws, size_t ws_size,
                              hipStream_t stream) {
  const float* full = (const float*)d_in[0];  // [2,2048,1024] fp32
  const float* ds   = (const float*)d_in[1];  // [2,1024,1024] fp32
  const float* Wq   = (const float*)d_in[2];
  const float* Wk   = (const float*)d_in[3];
  const float* Wv   = (const float*)d_in[4];
  const float* Wo   = (const float*)d_in[5];
  const float* bo   = (const float*)d_in[6];
  float* out = (float*)d_out;

  // ws layout (halfwords), 32 MB total:
  unsigned short* ws = (unsigned short*)d_ws;
  unsigned short* Qb  = ws;                     // [0,4M)   4096x1024
  unsigned short* Kb  = ws + (4u << 20);        // [4M,6M)  2048x1024
  unsigned short* Vt  = ws + (6u << 20);        // [6M,8M)  [B][1024 d][1024 kv]
  unsigned short* Ab  = ws + (8u << 20);        // [8M,12M) 4096x1024
  unsigned short* WT  = ws + (12u << 20);       // [12M,16M) WqT WkT WvT WoT
  unsigned short* WoT = WT + 3u * (1u << 20);

  prep<<<1024, 256, 0, stream>>>(Wq, Wk, Wv, Wo, WT);
  gemm_qkv<<<dim3(64, 8), 512, 0, stream>>>(full, ds, WT, Qb, Kb, Vt);
  attn_kernel<<<dim3(QN_ / 128, B_ * H_), 512, 0, stream>>>(Qb, Kb, Vt, Ab);
  gemm_o<<<dim3(64, 8), 512, 0, stream>>>(Ab, WoT, bo, out);
}